// Round 1
// baseline (924.965 us; speedup 1.0000x reference)
//
#include <hip/hip_runtime.h>
#include <hip/hip_bf16.h>
#include <math.h>

// Problem constants (fixed by the reference file)
#define NPTS 262144
#define NP   128
#define DD   64
#define NWORDS (NPTS / 64)   // 4096 u64 ballot words per plane

// AS(4) scalar pointers for small uniform reads (planes/BN). R7 lesson: use
// POD ext_vector for AS(4) vectors (HIP float4 ctors break the host pass).
#define AS4 __attribute__((address_space(4)))
typedef float evf4 __attribute__((ext_vector_type(4)));
typedef AS4 const float* csf;
typedef AS4 const evf4*  csf4;
#define TO_CSF(p)  ((csf)(unsigned long long)(const void*)(p))
#define TO_CSF4(p) ((csf4)(unsigned long long)(const void*)(p))

// ---------------------------------------------------------------------------
// Prep: pack plane params [P][12] (normal.xyz+offs | min.xyz | max.xyz),
// transpose w2 -> w2T[j][k], zero out_feats for the atomic-max pool.
// ---------------------------------------------------------------------------
__global__ __launch_bounds__(256) void prep_kernel(
    const float* __restrict__ plane_center, const float* __restrict__ plane_normal,
    const float* __restrict__ pmin, const float* __restrict__ pmax,
    const float* __restrict__ w2,
    float* __restrict__ packed, float* __restrict__ w2T,
    float* __restrict__ out_feats)
{
    const int t = threadIdx.x;
    out_feats[blockIdx.x * 256 + t] = 0.0f;          // grid = 64 blocks
    if (blockIdx.x == 0 && t < NP) {
        float n0 = plane_normal[t*3+0], n1 = plane_normal[t*3+1], n2 = plane_normal[t*3+2];
        float c0 = plane_center[t*3+0], c1 = plane_center[t*3+1], c2 = plane_center[t*3+2];
        float off = (c0*n0 + c1*n1) + c2*n2;          // matches jnp.sum order
        float4* pp = reinterpret_cast<float4*>(packed) + t * 3;
        pp[0] = make_float4(n0, n1, n2, off);
        pp[1] = make_float4(pmin[t*3+0], pmin[t*3+1], pmin[t*3+2], 0.0f);
        pp[2] = make_float4(pmax[t*3+0], pmax[t*3+1], pmax[t*3+2], 0.0f);
    }
    if (blockIdx.x == 1) {
#pragma unroll
        for (int u = 0; u < 16; ++u) {
            const int e = u * 256 + t;               // e = j*64 + k
            const int j = e >> 6, k = e & 63;
            w2T[e] = w2[k * DD + j];
        }
    }
}

// ---------------------------------------------------------------------------
// Fused per-point kernel, round-10: TWO POINTS PER THREAD.
// R9 theory update: the LDS return path is per-CU (~256 B/clk), so each
// wave-broadcast ds_read_b128 costs ~4 CU-cycles while the 4 FMAs it feeds
// cost only 2 CU-cycles of VALU issue (4 SIMDs / 2cyc-per-wave-instr) ->
// fc phase was ~2x oversubscribed on LDS broadcast BW (floor ~82us, not
// 41us). Fix: each thread computes 2 points (n, n+256) so every weight
// broadcast feeds 8 FMAs -> LDS demand per FLOP halves, LDS ~= VALU.
// Grid = 512 blocks = exactly 2 blocks/CU (no tail). FMA order per point is
// bit-identical to R9 -> absmax must stay 2.98e-8. __launch_bounds__(256,2)
// caps VGPR at 256 (est. ~170 used; 2 waves/EU is enough for a
// throughput-bound phase). Phase C amortizes plane s_loads over 2 points;
// the two mask/sm/on/off stores per array per plane are 256B+256B within a
// contiguous 2KB span -> same streaming-store behavior.
// ---------------------------------------------------------------------------
#define FMA4(ACC, FS, W, J) \
    ACC[4*(J)+0] = fmaf((FS), (W).x, ACC[4*(J)+0]); \
    ACC[4*(J)+1] = fmaf((FS), (W).y, ACC[4*(J)+1]); \
    ACC[4*(J)+2] = fmaf((FS), (W).z, ACC[4*(J)+2]); \
    ACC[4*(J)+3] = fmaf((FS), (W).w, ACC[4*(J)+3]);

__global__ __launch_bounds__(256, 2) void fused_kernel(
    const float* __restrict__ feature, const float* __restrict__ feature_geo,
    const float* __restrict__ xyz, const float* __restrict__ centers,
    const float* __restrict__ packed,
    const float* __restrict__ w1, const float* __restrict__ b1,
    const float* __restrict__ g1, const float* __restrict__ be1,
    const float* __restrict__ m1, const float* __restrict__ v1,
    const float* __restrict__ w2T, const float* __restrict__ b2,
    const float* __restrict__ g2, const float* __restrict__ be2,
    const float* __restrict__ m2, const float* __restrict__ v2,
    const float* __restrict__ w3, const float* __restrict__ b3,
    float* __restrict__ h2_out,
    float* __restrict__ out_sm, float* __restrict__ out_mask,
    float* __restrict__ out_on, float* __restrict__ out_off,
    unsigned long long* __restrict__ hitOn, unsigned long long* __restrict__ hitOff)
{
    __shared__ float sw1[128 * DD];   // 32 KB, row-major [k][j] like w1
    __shared__ float sw2[DD * DD];    // 16 KB, w2T layout [j][k]
    const int t = threadIdx.x;
    const int n0 = blockIdx.x * 512 + t;
    const int n1 = n0 + 256;
    const int lane = t & 63;
    const int word0 = n0 >> 6;        // wave-uniform; point1 word = word0 + 4

    // stage weights (coalesced float4; 12 per thread)
    {
        const float4* s1 = reinterpret_cast<const float4*>(w1);
        const float4* s2 = reinterpret_cast<const float4*>(w2T);
        float4* d1 = reinterpret_cast<float4*>(sw1);
        float4* d2 = reinterpret_cast<float4*>(sw2);
#pragma unroll
        for (int k = 0; k < 8; ++k) d1[t + k * 256] = s1[t + k * 256];
#pragma unroll
        for (int k = 0; k < 4; ++k) d2[t + k * 256] = s2[t + k * 256];
    }

    // cloud coords for both points (issue early; used in Phase C)
    const csf cc = TO_CSF(centers);
    const float ca0 = xyz[n0*3+0] + cc[0];
    const float ca1 = xyz[n0*3+1] + cc[1];
    const float ca2 = xyz[n0*3+2] + cc[2];
    const float cb0 = xyz[n1*3+0] + cc[0];
    const float cb1 = xyz[n1*3+1] + cc[1];
    const float cb2 = xyz[n1*3+2] + cc[2];

    __syncthreads();

    float acc0[DD], acc1[DD];
#pragma unroll
    for (int j = 0; j < DD; ++j) { acc0[j] = 0.0f; acc1[j] = 0.0f; }

    // ---- Phase A: fc1 from LDS (q rolled, j-blocks as 16x b128) ----
    const float4* fA0 = reinterpret_cast<const float4*>(feature) + (size_t)n0 * 16;
    const float4* fA1 = reinterpret_cast<const float4*>(feature) + (size_t)n1 * 16;
    const float4* fB0 = reinterpret_cast<const float4*>(feature_geo) + (size_t)n0 * 16;
    const float4* fB1 = reinterpret_cast<const float4*>(feature_geo) + (size_t)n1 * 16;
#pragma unroll 1
    for (int q = 0; q < 16; ++q) {
        const float4 f0 = fA0[q];
        const float4 f1 = fA1[q];
        const evf4* wr = reinterpret_cast<const evf4*>(sw1 + q * 4 * DD);
#pragma unroll
        for (int j4 = 0; j4 < 16; ++j4) { const evf4 w = wr[j4];
            FMA4(acc0, f0.x, w, j4) FMA4(acc1, f1.x, w, j4) }
#pragma unroll
        for (int j4 = 0; j4 < 16; ++j4) { const evf4 w = wr[16 + j4];
            FMA4(acc0, f0.y, w, j4) FMA4(acc1, f1.y, w, j4) }
#pragma unroll
        for (int j4 = 0; j4 < 16; ++j4) { const evf4 w = wr[32 + j4];
            FMA4(acc0, f0.z, w, j4) FMA4(acc1, f1.z, w, j4) }
#pragma unroll
        for (int j4 = 0; j4 < 16; ++j4) { const evf4 w = wr[48 + j4];
            FMA4(acc0, f0.w, w, j4) FMA4(acc1, f1.w, w, j4) }
    }
#pragma unroll 1
    for (int q = 0; q < 16; ++q) {
        const float4 f0 = fB0[q];
        const float4 f1 = fB1[q];
        const evf4* wr = reinterpret_cast<const evf4*>(sw1 + (DD + q * 4) * DD);
#pragma unroll
        for (int j4 = 0; j4 < 16; ++j4) { const evf4 w = wr[j4];
            FMA4(acc0, f0.x, w, j4) FMA4(acc1, f1.x, w, j4) }
#pragma unroll
        for (int j4 = 0; j4 < 16; ++j4) { const evf4 w = wr[16 + j4];
            FMA4(acc0, f0.y, w, j4) FMA4(acc1, f1.y, w, j4) }
#pragma unroll
        for (int j4 = 0; j4 < 16; ++j4) { const evf4 w = wr[32 + j4];
            FMA4(acc0, f0.z, w, j4) FMA4(acc1, f1.z, w, j4) }
#pragma unroll
        for (int j4 = 0; j4 < 16; ++j4) { const evf4 w = wr[48 + j4];
            FMA4(acc0, f0.w, w, j4) FMA4(acc1, f1.w, w, j4) }
    }
    // BN1 + ReLU in place (exact same per-point arithmetic/order as R9; the
    // scale sc is wave-uniform and shared between the two points)
    {
        const csf g1c = TO_CSF(g1), v1c = TO_CSF(v1), b1c = TO_CSF(b1),
                  m1c = TO_CSF(m1), be1c = TO_CSF(be1);
#pragma unroll
        for (int j = 0; j < DD; ++j) {
            float sc = g1c[j] * (1.0f / sqrtf(v1c[j] + 1e-5f));
            float h0 = fmaf(acc0[j] + b1c[j] - m1c[j], sc, be1c[j]);
            float h1 = fmaf(acc1[j] + b1c[j] - m1c[j], sc, be1c[j]);
            acc0[j] = fmaxf(h0, 0.0f);
            acc1[j] = fmaxf(h1, 0.0f);
        }
    }

    // ---- Phase B: fc2 from LDS w2T rows + BN2 + ReLU + fc3 + h2 store ----
    const csf g2c = TO_CSF(g2), v2c = TO_CSF(v2), b2c = TO_CSF(b2),
              m2c = TO_CSF(m2), be2c = TO_CSF(be2), w3c = TO_CSF(w3);
    float s0 = 0.0f, s1 = 0.0f;
    float4* o0 = reinterpret_cast<float4*>(h2_out) + (size_t)n0 * 16;
    float4* o1 = reinterpret_cast<float4*>(h2_out) + (size_t)n1 * 16;
#pragma unroll 1
    for (int jq = 0; jq < 16; ++jq) {
        const evf4* r0 = reinterpret_cast<const evf4*>(sw2 + (4*jq + 0) * DD);
        const evf4* r1 = reinterpret_cast<const evf4*>(sw2 + (4*jq + 1) * DD);
        const evf4* r2 = reinterpret_cast<const evf4*>(sw2 + (4*jq + 2) * DD);
        const evf4* r3 = reinterpret_cast<const evf4*>(sw2 + (4*jq + 3) * DD);
        float a00 = 0.0f, a01 = 0.0f, a02 = 0.0f, a03 = 0.0f;
        float a10 = 0.0f, a11 = 0.0f, a12 = 0.0f, a13 = 0.0f;
#pragma unroll
        for (int k4 = 0; k4 < 16; ++k4) {
            const evf4 w0 = r0[k4], w1v = r1[k4], w2v = r2[k4], w3v = r3[k4];
            {
                const float h0 = acc0[4*k4+0], h1v = acc0[4*k4+1],
                            h2v = acc0[4*k4+2], h3v = acc0[4*k4+3];
                a00 = fmaf(h0, w0.x, a00); a00 = fmaf(h1v, w0.y, a00);
                a00 = fmaf(h2v, w0.z, a00); a00 = fmaf(h3v, w0.w, a00);
                a01 = fmaf(h0, w1v.x, a01); a01 = fmaf(h1v, w1v.y, a01);
                a01 = fmaf(h2v, w1v.z, a01); a01 = fmaf(h3v, w1v.w, a01);
                a02 = fmaf(h0, w2v.x, a02); a02 = fmaf(h1v, w2v.y, a02);
                a02 = fmaf(h2v, w2v.z, a02); a02 = fmaf(h3v, w2v.w, a02);
                a03 = fmaf(h0, w3v.x, a03); a03 = fmaf(h1v, w3v.y, a03);
                a03 = fmaf(h2v, w3v.z, a03); a03 = fmaf(h3v, w3v.w, a03);
            }
            {
                const float h0 = acc1[4*k4+0], h1v = acc1[4*k4+1],
                            h2v = acc1[4*k4+2], h3v = acc1[4*k4+3];
                a10 = fmaf(h0, w0.x, a10); a10 = fmaf(h1v, w0.y, a10);
                a10 = fmaf(h2v, w0.z, a10); a10 = fmaf(h3v, w0.w, a10);
                a11 = fmaf(h0, w1v.x, a11); a11 = fmaf(h1v, w1v.y, a11);
                a11 = fmaf(h2v, w1v.z, a11); a11 = fmaf(h3v, w1v.w, a11);
                a12 = fmaf(h0, w2v.x, a12); a12 = fmaf(h1v, w2v.y, a12);
                a12 = fmaf(h2v, w2v.z, a12); a12 = fmaf(h3v, w2v.w, a12);
                a13 = fmaf(h0, w3v.x, a13); a13 = fmaf(h1v, w3v.y, a13);
                a13 = fmaf(h2v, w3v.z, a13); a13 = fmaf(h3v, w3v.w, a13);
            }
        }
        float hv0[4] = {a00, a01, a02, a03};
        float hv1[4] = {a10, a11, a12, a13};
#pragma unroll
        for (int u = 0; u < 4; ++u) {
            const int jj = 4*jq + u;
            float sc = g2c[jj] * (1.0f / sqrtf(v2c[jj] + 1e-5f));
            float h0 = fmaf(hv0[u] + b2c[jj] - m2c[jj], sc, be2c[jj]);
            float h1 = fmaf(hv1[u] + b2c[jj] - m2c[jj], sc, be2c[jj]);
            h0 = fmaxf(h0, 0.0f);
            h1 = fmaxf(h1, 0.0f);
            hv0[u] = h0; hv1[u] = h1;
            s0 = fmaf(h0, w3c[jj], s0);
            s1 = fmaf(h1, w3c[jj], s1);
        }
        o0[jq] = make_float4(hv0[0], hv0[1], hv0[2], hv0[3]);
        o1[jq] = make_float4(hv1[0], hv1[1], hv1[2], hv1[3]);
    }
    const float bb3 = TO_CSF(b3)[0];
    const float score0 = fmaxf(s0 + bb3, 0.0f);
    const float score1 = fmaxf(s1 + bb3, 0.0f);

    // sigmoid(score) > 0.5 via XLA-style logistic expansion (score >= 0)
    const bool on0 = (0.5f + 0.5f * tanhf(0.5f * score0)) > 0.5f;
    const bool on1 = (0.5f + 0.5f * tanhf(0.5f * score1)) > 0.5f;

    // ---- Phase C: geometry + 4x2 output stores + 2x2 ballots per plane ----
    const csf4 pp = TO_CSF4(packed);
#pragma unroll 1
    for (int p = 0; p < NP; ++p) {
        const evf4 nrm = pp[p*3+0];
        const evf4 mn  = pp[p*3+1];
        const evf4 mx  = pp[p*3+2];
        // point 0
        float dA = fabsf(fmaf(ca2, nrm.z, fmaf(ca1, nrm.y, ca0 * nrm.x)) - nrm.w);
        bool okA0 = (mx.x == 0.0f) | ((ca0 >= mn.x) & (ca0 < mx.x));
        bool okA1 = (mx.y == 0.0f) | ((ca1 >= mn.y) & (ca1 < mx.y));
        bool okA2 = (mx.z == 0.0f) | ((ca2 >= mn.z) & (ca2 < mx.z));
        bool mkA  = okA0 & okA1 & okA2 & (dA < 0.1f);
        // point 1
        float dB = fabsf(fmaf(cb2, nrm.z, fmaf(cb1, nrm.y, cb0 * nrm.x)) - nrm.w);
        bool okB0 = (mx.x == 0.0f) | ((cb0 >= mn.x) & (cb0 < mx.x));
        bool okB1 = (mx.y == 0.0f) | ((cb1 >= mn.y) & (cb1 < mx.y));
        bool okB2 = (mx.z == 0.0f) | ((cb2 >= mn.z) & (cb2 < mx.z));
        bool mkB  = okB0 & okB1 & okB2 & (dB < 0.1f);

        const size_t idxA = (size_t)p * NPTS + n0;   // idxB = idxA + 256
        const bool monA  = mkA & on0;
        const bool moffA = mkA & (!on0);
        const bool monB  = mkB & on1;
        const bool moffB = mkB & (!on1);
        out_mask[idxA]       = mkA ? 1.0f : 0.0f;
        out_mask[idxA + 256] = mkB ? 1.0f : 0.0f;
        out_sm[idxA]         = mkA ? score0 : 0.0f;
        out_sm[idxA + 256]   = mkB ? score1 : 0.0f;
        out_on[idxA]         = monA ? 1.0f : 0.0f;
        out_on[idxA + 256]   = monB ? 1.0f : 0.0f;
        out_off[idxA]        = moffA ? 1.0f : 0.0f;
        out_off[idxA + 256]  = moffB ? 1.0f : 0.0f;
        unsigned long long bOnA  = __ballot(monA);
        unsigned long long bOffA = __ballot(moffA);
        unsigned long long bOnB  = __ballot(monB);
        unsigned long long bOffB = __ballot(moffB);
        if (lane == 0) {
            hitOn [(size_t)p * NWORDS + word0]     = bOnA;
            hitOn [(size_t)p * NWORDS + word0 + 4] = bOnB;
            hitOff[(size_t)p * NWORDS + word0]     = bOffA;
            hitOff[(size_t)p * NWORDS + word0 + 4] = bOffB;
        }
    }
}

// ---------------------------------------------------------------------------
// Pool: masked max of h2 per plane, register-accumulated per block, then
// atomicMax(int) into out_feats (non-negative IEEE floats compare as signed
// ints; h2 >= 0; zero-init by prep -> exact where(any,max,0) semantics).
// Wave w owns planes [32w,32w+32); lane = dim; hit loop is wave-uniform.
// tile[n*64+lane]: 2-way bank alias = free (m136).
// ---------------------------------------------------------------------------
__global__ __launch_bounds__(256) void pool_kernel(
    const float* __restrict__ h2,
    const unsigned long long* __restrict__ hitOn,
    const unsigned long long* __restrict__ hitOff,
    int* __restrict__ out_feats_i)
{
    __shared__ float tile[128 * DD];                 // 32 KB
    __shared__ unsigned long long bm[2][NP][2];      // 4 KB
    const int t = threadIdx.x;
    const int lane = t & 63;
    const int wv = t >> 6;

    float accOn[32], accOff[32];
#pragma unroll
    for (int i = 0; i < 32; ++i) { accOn[i] = 0.0f; accOff[i] = 0.0f; }

    for (int cc = 0; cc < 4; ++cc) {
        const int chunk = blockIdx.x * 4 + cc;       // 0..2047
        const int base  = chunk * 128;
        const float4* src = reinterpret_cast<const float4*>(h2 + (size_t)base * DD);
        float4* dst = reinterpret_cast<float4*>(tile);
#pragma unroll
        for (int q = 0; q < 8; ++q) dst[t + q * 256] = src[t + q * 256];
        {
            const int p = t & 127;
            const int half = t >> 7;
            const unsigned long long* hsrc = half ? hitOff : hitOn;
            const int w0 = chunk * 2;
            bm[half][p][0] = hsrc[(size_t)p * NWORDS + w0 + 0];
            bm[half][p][1] = hsrc[(size_t)p * NWORDS + w0 + 1];
        }
        __syncthreads();

#pragma unroll
        for (int i = 0; i < 32; ++i) {
            const int p = wv * 32 + i;
            unsigned long long m;
            m = bm[0][p][0];
            while (m) { int nn = __builtin_ctzll(m); m &= m - 1;
                        accOn[i]  = fmaxf(accOn[i],  tile[nn * DD + lane]); }
            m = bm[0][p][1];
            while (m) { int nn = __builtin_ctzll(m); m &= m - 1;
                        accOn[i]  = fmaxf(accOn[i],  tile[(64 + nn) * DD + lane]); }
            m = bm[1][p][0];
            while (m) { int nn = __builtin_ctzll(m); m &= m - 1;
                        accOff[i] = fmaxf(accOff[i], tile[nn * DD + lane]); }
            m = bm[1][p][1];
            while (m) { int nn = __builtin_ctzll(m); m &= m - 1;
                        accOff[i] = fmaxf(accOff[i], tile[(64 + nn) * DD + lane]); }
        }
        __syncthreads();
    }
#pragma unroll
    for (int i = 0; i < 32; ++i) {
        const int p = wv * 32 + i;
        if (accOn[i]  != 0.0f) atomicMax(&out_feats_i[p * DD + lane],            __float_as_int(accOn[i]));
        if (accOff[i] != 0.0f) atomicMax(&out_feats_i[NP * DD + p * DD + lane],  __float_as_int(accOff[i]));
    }
}

extern "C" void kernel_launch(void* const* d_in, const int* in_sizes, int n_in,
                              void* d_out, int out_size, void* d_ws, size_t ws_size,
                              hipStream_t stream) {
    const float* feature      = (const float*)d_in[0];
    const float* feature_geo  = (const float*)d_in[1];
    const float* xyz          = (const float*)d_in[2];
    const float* centers      = (const float*)d_in[3];
    const float* plane_center = (const float*)d_in[4];
    const float* plane_normal = (const float*)d_in[5];
    const float* pmin         = (const float*)d_in[6];
    const float* pmax         = (const float*)d_in[7];
    const float* w1 = (const float*)d_in[8];
    const float* b1 = (const float*)d_in[9];
    const float* g1 = (const float*)d_in[10];
    const float* be1 = (const float*)d_in[11];
    const float* m1 = (const float*)d_in[12];
    const float* v1 = (const float*)d_in[13];
    const float* w2 = (const float*)d_in[14];
    const float* b2 = (const float*)d_in[15];
    const float* g2 = (const float*)d_in[16];
    const float* be2 = (const float*)d_in[17];
    const float* m2 = (const float*)d_in[18];
    const float* v2 = (const float*)d_in[19];
    const float* w3 = (const float*)d_in[20];
    const float* b3 = (const float*)d_in[21];

    float* out = (float*)d_out;
    const size_t PN = (size_t)NP * NPTS;
    float* out_sm    = out;
    float* out_mask  = out + PN;
    float* out_on    = out + 2 * PN;
    float* out_off   = out + 3 * PN;
    float* out_feats = out + 4 * PN;

    // workspace carve (~73 MB)
    float* h2     = (float*)d_ws;                                // N*64 f32 (64 MB)
    unsigned long long* hitOn  = (unsigned long long*)(h2 + (size_t)NPTS * DD);
    unsigned long long* hitOff = hitOn + (size_t)NP * NWORDS;
    float* packed = (float*)(hitOff + (size_t)NP * NWORDS);      // P*12 f32
    float* w2T    = packed + NP * 12;                            // 64*64 f32

    prep_kernel<<<64, 256, 0, stream>>>(
        plane_center, plane_normal, pmin, pmax, w2, packed, w2T, out_feats);
    fused_kernel<<<NPTS / 512, 256, 0, stream>>>(
        feature, feature_geo, xyz, centers, packed,
        w1, b1, g1, be1, m1, v1, w2T, b2, g2, be2, m2, v2, w3, b3,
        h2, out_sm, out_mask, out_on, out_off, hitOn, hitOff);
    pool_kernel<<<512, 256, 0, stream>>>(h2, hitOn, hitOff, (int*)out_feats);
}